// Round 2
// baseline (1711.581 us; speedup 1.0000x reference)
//
#include <hip/hip_runtime.h>
#include <hip/hip_bf16.h>
#include <float.h>

#define Npts 16384
#define Dims 64
#define Oout 128
#define KNN  10
#define KC   16                      // coarse top-K carried to exact fp64 re-rank
#define SEG  4
#define QT   64
#define CT   64
#define CAND_PER_SEG (Npts / SEG)    // 4096
#define CHUNKS (CAND_PER_SEG / CT)   // 64

// ---------------- kernel 1: sq[j] = ||pts[j]||^2 ----------------
__global__ __launch_bounds__(256) void k_sq(const float* __restrict__ x,
                                            float* __restrict__ sq) {
    int n = blockIdx.x * 256 + threadIdx.x;
    float a = 0.f;
#pragma unroll
    for (int d = 0; d < Dims; ++d) {
        float v = x[d * Npts + n];
        a = fmaf(v, v, a);
    }
    sq[n] = a;
}

// ---------------- kernel 1b: ptsT[n][d] = x[d][n] (LDS tile transpose) ----------------
__global__ __launch_bounds__(256) void k_tr(const float* __restrict__ x,
                                            float* __restrict__ ptsT) {
    __shared__ float tile[64][65];
    const int b = blockIdx.x;            // 256 blocks x 64 points
    for (int i = threadIdx.x; i < 64 * 64; i += 256) {
        int d = i >> 6, p = i & 63;
        tile[d][p] = x[d * Npts + b * 64 + p];     // coalesced on p
    }
    __syncthreads();
    for (int i = threadIdx.x; i < 64 * 64; i += 256) {
        int p = i >> 6, d = i & 63;
        ptsT[(b * 64 + p) * 64 + d] = tile[d][p];  // coalesced on d
    }
}

// ---------------- kernel 2: y[n][o] = W[o]·pts[n] + b[o] ----------------
__global__ __launch_bounds__(128) void k_y(const float* __restrict__ x,
                                           const float* __restrict__ W,
                                           const float* __restrict__ b,
                                           float* __restrict__ y) {
    int n = blockIdx.x;
    int o = threadIdx.x;
    float acc = b[o];
#pragma unroll
    for (int d = 0; d < Dims; ++d)
        acc = fmaf(x[d * Npts + n], W[o * Dims + d], acc);
    y[n * Oout + o] = acc;
}

// ---------------- kernel 3: per-segment coarse top-16 KNN (fp32) ----------------
// grid: 256 query-blocks x SEG segments. block=256 threads.
__global__ __launch_bounds__(256) void k_knn(const float* __restrict__ x,
                                             const float* __restrict__ sq,
                                             float* __restrict__ knnD,
                                             int* __restrict__ knnI) {
    __shared__ float qbuf[Dims][QT];      // [d][q] 16 KB
    __shared__ float cbuf[Dims][CT];      // [d][c] 16 KB
    __shared__ float sbuf[QT][CT + 1];    // padded stride 65
    __shared__ float sqc[CT];

    const int t     = threadIdx.x;
    const int qblk  = blockIdx.x & 255;
    const int seg   = blockIdx.x >> 8;
    const int qbase = qblk * QT;
    const int tx    = t & 15;
    const int ty    = t >> 4;

    for (int i = t; i < Dims * QT; i += 256) {
        int d = i >> 6, q = i & 63;
        qbuf[d][q] = x[d * Npts + qbase + q];
    }

    // register-resident sorted coarse top-16 (ascending), compile-time indices only
    float bd[KC];
    int   bi[KC];
#pragma unroll
    for (int k = 0; k < KC; ++k) { bd[k] = FLT_MAX; bi[k] = -1; }

    const int selq = t & 63;   // query this thread selects for
    const int sels = t >> 6;   // 16-candidate slice within each chunk

    for (int ci = 0; ci < CHUNKS; ++ci) {
        const int jbase = seg * CAND_PER_SEG + ci * CT;

        for (int i = t; i < Dims * CT; i += 256) {
            int d = i >> 6, c = i & 63;
            cbuf[d][c] = x[d * Npts + jbase + c];
        }
        if (t < CT) sqc[t] = sq[jbase + t];
        __syncthreads();  // B1

        float acc[4][4];
#pragma unroll
        for (int a = 0; a < 4; ++a)
#pragma unroll
            for (int c = 0; c < 4; ++c) acc[a][c] = 0.f;

#pragma unroll 16
        for (int d = 0; d < Dims; ++d) {
            const float4 qv = *reinterpret_cast<const float4*>(&qbuf[d][ty * 4]);
            const float4 cv = *reinterpret_cast<const float4*>(&cbuf[d][tx * 4]);
            const float qa[4] = {qv.x, qv.y, qv.z, qv.w};
            const float ca[4] = {cv.x, cv.y, cv.z, cv.w};
#pragma unroll
            for (int a = 0; a < 4; ++a)
#pragma unroll
                for (int c = 0; c < 4; ++c)
                    acc[a][c] = fmaf(qa[a], ca[c], acc[a][c]);
        }

        // coarse score s = sq[j] - 2*dot  (same ranking as d2 per query)
        const float4 sqv = *reinterpret_cast<const float4*>(&sqc[tx * 4]);
        const float sqa[4] = {sqv.x, sqv.y, sqv.z, sqv.w};
#pragma unroll
        for (int a = 0; a < 4; ++a)
#pragma unroll
            for (int c = 0; c < 4; ++c)
                sbuf[ty * 4 + a][tx * 4 + c] = fmaf(-2.f, acc[a][c], sqa[c]);
        __syncthreads();  // B2

        const int cb = sels * 16;
#pragma unroll
        for (int c = 0; c < 16; ++c) {
            float s = sbuf[selq][cb + c];
            if (s < bd[KC - 1]) {
                int j = jbase + cb + c;
#pragma unroll
                for (int k = KC - 1; k >= 1; --k) {
                    bool up = bd[k - 1] > s;
                    float nd = up ? bd[k - 1] : ((bd[k] > s) ? s : bd[k]);
                    int   ni = up ? bi[k - 1] : ((bd[k] > s) ? j : bi[k]);
                    bd[k] = nd; bi[k] = ni;
                }
                bool u0 = bd[0] > s;
                bi[0] = u0 ? j : bi[0];
                bd[0] = u0 ? s : bd[0];
            }
        }
        __syncthreads();  // B3
    }

    // merge the 4 per-thread sorted lists per query -> per-(segment,query) top-16
    float* mDp = &qbuf[0][0];          // 64*4*16 = 4096 floats == qbuf capacity
    int*   mIp = (int*)&cbuf[0][0];
#pragma unroll
    for (int k = 0; k < KC; ++k) {
        mDp[selq * (4 * KC) + sels * KC + k] = bd[k];
        mIp[selq * (4 * KC) + sels * KC + k] = bi[k];
    }
    __syncthreads();

    if (t < QT) {
        const int base = t * (4 * KC);
        int p0 = 0, p1 = 0, p2 = 0, p3 = 0;
        const int gbase = ((seg * Npts) + qbase + t) * KC;
        for (int k = 0; k < KC; ++k) {
            float v0 = (p0 < KC) ? mDp[base + p0]           : FLT_MAX;
            float v1 = (p1 < KC) ? mDp[base + KC + p1]      : FLT_MAX;
            float v2 = (p2 < KC) ? mDp[base + 2 * KC + p2]  : FLT_MAX;
            float v3 = (p3 < KC) ? mDp[base + 3 * KC + p3]  : FLT_MAX;
            float bv = v0; int bs = 0;
            if (v1 < bv) { bv = v1; bs = 1; }
            if (v2 < bv) { bv = v2; bs = 2; }
            if (v3 < bv) { bv = v3; bs = 3; }
            int off = (bs == 0) ? p0 : (bs == 1) ? p1 : (bs == 2) ? p2 : p3;
            knnD[gbase + k] = bv;
            knnI[gbase + k] = mIp[base + bs * KC + off];
            if (bs == 0) ++p0; else if (bs == 1) ++p1; else if (bs == 2) ++p2; else ++p3;
        }
    }
}

// ---------------- kernel 4: 4-way merge -> fp64 exact re-rank -> gather-max ----------------
__global__ __launch_bounds__(128) void k_out(const float* __restrict__ y,
                                             const float* __restrict__ ptsT,
                                             const float* __restrict__ knnD,
                                             const int* __restrict__ knnI,
                                             float* __restrict__ out) {
    __shared__ int    cidx[KC];
    __shared__ double d2s[KC];
    __shared__ float  qs[Dims];
    __shared__ int    nb[KNN];
    const int n = blockIdx.x;
    const int t = threadIdx.x;

    if (t < Dims) qs[t] = ptsT[n * Dims + t];

    if (t == 0) {
        // 4-way merge of per-segment sorted coarse lists -> global coarse top-16
        int p0 = 0, p1 = 0, p2 = 0, p3 = 0;
        for (int k = 0; k < KC; ++k) {
            float v0 = (p0 < KC) ? knnD[(0 * Npts + n) * KC + p0] : FLT_MAX;
            float v1 = (p1 < KC) ? knnD[(1 * Npts + n) * KC + p1] : FLT_MAX;
            float v2 = (p2 < KC) ? knnD[(2 * Npts + n) * KC + p2] : FLT_MAX;
            float v3 = (p3 < KC) ? knnD[(3 * Npts + n) * KC + p3] : FLT_MAX;
            float bv = v0; int bs = 0;
            if (v1 < bv) { bv = v1; bs = 1; }
            if (v2 < bv) { bv = v2; bs = 2; }
            if (v3 < bv) { bv = v3; bs = 3; }
            int off = (bs == 0) ? p0 : (bs == 1) ? p1 : (bs == 2) ? p2 : p3;
            cidx[k] = knnI[(bs * Npts + n) * KC + off];
            if (bs == 0) ++p0; else if (bs == 1) ++p1; else if (bs == 2) ++p2; else ++p3;
        }
    }
    __syncthreads();

    // exact fp64 squared distance for the 16 coarse candidates (no cancellation)
    if (t < KC) {
        const int j = cidx[t];
        double acc = 0.0;
#pragma unroll
        for (int d4 = 0; d4 < Dims / 4; ++d4) {
            const float4 pv = *reinterpret_cast<const float4*>(&ptsT[j * Dims + d4 * 4]);
            const float4 qv = *reinterpret_cast<const float4*>(&qs[d4 * 4]);
            double e0 = (double)qv.x - (double)pv.x;
            double e1 = (double)qv.y - (double)pv.y;
            double e2 = (double)qv.z - (double)pv.z;
            double e3 = (double)qv.w - (double)pv.w;
            acc = fma(e0, e0, acc);
            acc = fma(e1, e1, acc);
            acc = fma(e2, e2, acc);
            acc = fma(e3, e3, acc);
        }
        d2s[t] = acc;
    }
    __syncthreads();

    // exact top-10 selection (ties -> lowest index, matching top_k)
    if (t == 0) {
        unsigned used = 0;
        for (int k = 0; k < KNN; ++k) {
            double best = DBL_MAX; int bc = 0; int bidx = 0x7fffffff;
            for (int c = 0; c < KC; ++c) {
                if (used & (1u << c)) continue;
                double v = d2s[c]; int j = cidx[c];
                if (v < best || (v == best && j < bidx)) { best = v; bc = c; bidx = j; }
            }
            used |= 1u << bc;
            nb[k] = bidx;
        }
    }
    __syncthreads();

    float m = -FLT_MAX;
#pragma unroll
    for (int k = 0; k < KNN; ++k)
        m = fmaxf(m, y[nb[k] * Oout + t]);
    out[n * Oout + t] = m;   // fp32 output (reference output dtype is float32)
}

// ---------------- launcher ----------------
extern "C" void kernel_launch(void* const* d_in, const int* in_sizes, int n_in,
                              void* d_out, int out_size, void* d_ws, size_t ws_size,
                              hipStream_t stream) {
    const float* x = (const float*)d_in[0];   // (1, 64, 16384)
    const float* W = (const float*)d_in[1];   // (128, 64)
    const float* b = (const float*)d_in[2];   // (128,)
    float* out = (float*)d_out;

    float* ws   = (float*)d_ws;
    float* sq   = ws;                                   // N
    float* ptsT = ws + Npts;                            // N*D
    float* y    = ptsT + Npts * Dims;                   // N*O
    float* knnD = y + Npts * Oout;                      // SEG*N*KC
    int*   knnI = (int*)(knnD + SEG * Npts * KC);       // SEG*N*KC

    k_sq <<<Npts / 256, 256, 0, stream>>>(x, sq);
    k_tr <<<Npts / 64, 256, 0, stream>>>(x, ptsT);
    k_y  <<<Npts, 128, 0, stream>>>(x, W, b, y);
    k_knn<<<(Npts / QT) * SEG, 256, 0, stream>>>(x, sq, knnD, knnI);
    k_out<<<Npts, 128, 0, stream>>>(y, ptsT, knnD, knnI, out);
}

// Round 3
// 988.518 us; speedup vs baseline: 1.7315x; 1.7315x over previous
//
#include <hip/hip_runtime.h>
#include <hip/hip_bf16.h>
#include <float.h>

#define Npts 16384
#define Dims 64
#define Oout 128
#define KNN  10
#define KC   16                      // coarse top-K per (segment, query)
#define SEG  4
#define QT   64                      // queries per k_knn block
#define CT   64                      // candidates per chunk
#define CAND_PER_SEG (Npts / SEG)    // 4096
#define CHUNKS (CAND_PER_SEG / CT)   // 64

typedef __attribute__((ext_vector_type(8))) short s16x8;
typedef __attribute__((ext_vector_type(4))) float f32x4;

// bf16 round-to-nearest-even, bit-level (no header API dependence)
__device__ __forceinline__ unsigned short f2bf(float f) {
    unsigned u = __float_as_uint(f);
    return (unsigned short)((u + 0x7FFFu + ((u >> 16) & 1u)) >> 16);
}
__device__ __forceinline__ float bf2f(unsigned short b) {
    return __uint_as_float(((unsigned)b) << 16);
}

__device__ __forceinline__ void gl_lds16(const void* g, void* s) {
    __builtin_amdgcn_global_load_lds(
        (const __attribute__((address_space(1))) void*)g,
        (__attribute__((address_space(3))) void*)s,
        16, 0, 0);
}

__device__ __forceinline__ void insert16(float (&bd)[KC], int (&bi)[KC], float s, int j) {
    if (s < bd[KC - 1]) {
#pragma unroll
        for (int k = KC - 1; k >= 1; --k) {
            bool up = bd[k - 1] > s;
            float nd = up ? bd[k - 1] : ((bd[k] > s) ? s : bd[k]);
            int   ni = up ? bi[k - 1] : ((bd[k] > s) ? j : bi[k]);
            bd[k] = nd; bi[k] = ni;
        }
        bool u0 = bd[0] > s;
        bi[0] = u0 ? j : bi[0];
        bd[0] = u0 ? s : bd[0];
    }
}

// ------- k_tr: transpose + bf16 hi/lo split + sq, all from x -------
__global__ __launch_bounds__(256) void k_tr(const float* __restrict__ x,
                                            float* __restrict__ ptsT,
                                            unsigned short* __restrict__ xh,
                                            unsigned short* __restrict__ xl,
                                            float* __restrict__ sq) {
    __shared__ float tile[64][65];
    const int b = blockIdx.x;            // 256 blocks x 64 points
    for (int i = threadIdx.x; i < 64 * 64; i += 256) {
        int d = i >> 6, p = i & 63;
        tile[d][p] = x[d * Npts + b * 64 + p];     // coalesced on p
    }
    __syncthreads();
    for (int i = threadIdx.x; i < 64 * 64; i += 256) {
        int p = i >> 6, d = i & 63;
        float v = tile[d][p];
        ptsT[(b * 64 + p) * 64 + d] = v;           // coalesced on d
        unsigned short h = f2bf(v);
        float lo = v - bf2f(h);
        xh[(b * 64 + p) * 64 + d] = h;
        xl[(b * 64 + p) * 64 + d] = f2bf(lo);
    }
    __syncthreads();
    if (threadIdx.x < 64) {
        int p = threadIdx.x;
        float a = 0.f;
#pragma unroll
        for (int d = 0; d < 64; ++d) { float v = tile[d][p]; a = fmaf(v, v, a); }
        sq[b * 64 + p] = a;
    }
}

// ------- k_y: y[n][o] = W[o]·pts[n] + b[o], LDS-tiled -------
__global__ __launch_bounds__(256) void k_y(const float* __restrict__ ptsT,
                                           const float* __restrict__ W,
                                           const float* __restrict__ bias,
                                           float* __restrict__ y) {
    __shared__ float wsh[128][65];
    __shared__ float xs[8][64];
    const int t = threadIdx.x;
    const int nb = blockIdx.x * 8;
    for (int i = t; i < 128 * 64; i += 256) {
        int o = i >> 6, d = i & 63;
        wsh[o][d] = W[i];
    }
    for (int i = t; i < 8 * 64; i += 256) {
        int n8 = i >> 6, d = i & 63;
        xs[n8][d] = ptsT[(nb + n8) * 64 + d];
    }
    __syncthreads();
    const int o = t & 127, nn = t >> 7;
    float a0 = bias[o], a1 = a0, a2 = a0, a3 = a0;
#pragma unroll
    for (int d = 0; d < 64; ++d) {
        float wv = wsh[o][d];
        a0 = fmaf(xs[nn * 4 + 0][d], wv, a0);
        a1 = fmaf(xs[nn * 4 + 1][d], wv, a1);
        a2 = fmaf(xs[nn * 4 + 2][d], wv, a2);
        a3 = fmaf(xs[nn * 4 + 3][d], wv, a3);
    }
    y[(nb + nn * 4 + 0) * 128 + o] = a0;
    y[(nb + nn * 4 + 1) * 128 + o] = a1;
    y[(nb + nn * 4 + 2) * 128 + o] = a2;
    y[(nb + nn * 4 + 3) * 128 + o] = a3;
}

// ------- k_knn: split-bf16 MFMA distances + in-register top-16 -------
// grid: 256 qblocks x SEG. block 256 = 4 waves; wave w owns queries w*16..+15.
// S^T = mfma(A=cand, B=query): lane holds 16 scores, all for query (lane&15).
__global__ __launch_bounds__(256, 4) void k_knn(const unsigned short* __restrict__ xh,
                                                const unsigned short* __restrict__ xl,
                                                const float* __restrict__ sq,
                                                int* __restrict__ knnI) {
    __shared__ char smem[2 * 16384];   // 2 bufs x (hi 8KB + lo 8KB), swizzled
    const int t    = threadIdx.x;
    const int w    = t >> 6;
    const int l    = t & 63;
    const int g    = l >> 4;           // k-group / C-row group
    const int q15  = l & 15;           // query column within wave
    const int qblk = blockIdx.x & 255;
    const int seg  = blockIdx.x >> 8;
    const int qbase = qblk * QT;
    const int swz  = (l & 7) << 4;     // A-read XOR swizzle (c&7 == l&7)

    // B frags (queries): 8 contiguous k per lane, k = g*8.. ; one-time global loads
    const int q = qbase + w * 16 + q15;
    const char* qhp = (const char*)xh + (size_t)q * 128;
    const char* qlp = (const char*)xl + (size_t)q * 128;
    const s16x8 qh0 = *(const s16x8*)(qhp + g * 16);
    const s16x8 qh1 = *(const s16x8*)(qhp + 64 + g * 16);
    const s16x8 ql0 = *(const s16x8*)(qlp + g * 16);
    const s16x8 ql1 = *(const s16x8*)(qlp + 64 + g * 16);

    // staging source lane offset: row = (l>>3), slot = (l&7)^(row&7) pre-swizzle
    const int loff = ((l >> 3) << 7) + (((l & 7) ^ (l >> 3)) << 4);

    float bd[KC]; int bi[KC];
#pragma unroll
    for (int k = 0; k < KC; ++k) { bd[k] = FLT_MAX; bi[k] = -1; }

    // prologue: stage chunk 0 into buf 0
    {
        const size_t sb = (size_t)(seg * CAND_PER_SEG + w * 16) * 128 + loff;
        const char* sH = (const char*)xh + sb;
        const char* sL = (const char*)xl + sb;
        char* dH = smem + w * 2048;
        gl_lds16(sH, dH);           gl_lds16(sH + 1024, dH + 1024);
        gl_lds16(sL, dH + 8192);    gl_lds16(sL + 1024, dH + 9216);
    }
    __syncthreads();

    for (int c = 0; c < CHUNKS; ++c) {
        if (c + 1 < CHUNKS) {   // stage next chunk into other buffer
            const size_t sb = (size_t)(seg * CAND_PER_SEG + (c + 1) * CT + w * 16) * 128 + loff;
            const char* sH = (const char*)xh + sb;
            const char* sL = (const char*)xl + sb;
            char* dH = smem + ((c + 1) & 1) * 16384 + w * 2048;
            gl_lds16(sH, dH);           gl_lds16(sH + 1024, dH + 1024);
            gl_lds16(sL, dH + 8192);    gl_lds16(sL + 1024, dH + 9216);
        }

        const char* hb = smem + (c & 1) * 16384;
        const char* lb = hb + 8192;
        const int jb = seg * CAND_PER_SEG + c * CT;
#pragma unroll
        for (int ct = 0; ct < 4; ++ct) {
            const int ro = (ct * 16 + q15) * 128;
            const int o0 = (g * 16) ^ swz;
            const int o1 = (64 + g * 16) ^ swz;
            const s16x8 ah0 = *(const s16x8*)(hb + ro + o0);
            const s16x8 ah1 = *(const s16x8*)(hb + ro + o1);
            const s16x8 al0 = *(const s16x8*)(lb + ro + o0);
            const s16x8 al1 = *(const s16x8*)(lb + ro + o1);
            f32x4 acc = {0.f, 0.f, 0.f, 0.f};
            acc = __builtin_amdgcn_mfma_f32_16x16x32_bf16(ah0, qh0, acc, 0, 0, 0);
            acc = __builtin_amdgcn_mfma_f32_16x16x32_bf16(ah1, qh1, acc, 0, 0, 0);
            acc = __builtin_amdgcn_mfma_f32_16x16x32_bf16(ah0, ql0, acc, 0, 0, 0);
            acc = __builtin_amdgcn_mfma_f32_16x16x32_bf16(ah1, ql1, acc, 0, 0, 0);
            acc = __builtin_amdgcn_mfma_f32_16x16x32_bf16(al0, qh0, acc, 0, 0, 0);
            acc = __builtin_amdgcn_mfma_f32_16x16x32_bf16(al1, qh1, acc, 0, 0, 0);
            // scores: s = sq[j] - 2*dot  (sq from global, L2-hot; off the LDS pipe)
            const int j0 = jb + ct * 16 + g * 4;
            const float4 s4 = *(const float4*)(sq + j0);
            insert16(bd, bi, fmaf(-2.f, acc[0], s4.x), j0 + 0);
            insert16(bd, bi, fmaf(-2.f, acc[1], s4.y), j0 + 1);
            insert16(bd, bi, fmaf(-2.f, acc[2], s4.z), j0 + 2);
            insert16(bd, bi, fmaf(-2.f, acc[3], s4.w), j0 + 3);
        }
        __syncthreads();   // drains staging loads (vmcnt 0) + syncs buffer swap
    }

    // merge 4 per-lane sorted lists per query (lanes q,q+16,q+32,q+48 of this wave)
    float* mD = (float*)smem;            // 64q x 4g x 16 = 4096 floats (16KB)
    int*   mI = (int*)(smem + 16384);
    const int qb = w * 16 + q15;
#pragma unroll
    for (int k = 0; k < KC; ++k) {
        mD[(qb * 4 + g) * KC + k] = bd[k];
        mI[(qb * 4 + g) * KC + k] = bi[k];
    }
    __syncthreads();

    if (t < QT) {
        const int base = t * 4 * KC;
        int p0 = 0, p1 = 0, p2 = 0, p3 = 0;
        int* outp = knnI + (size_t)(seg * Npts + qbase + t) * KC;
        for (int k = 0; k < KC; ++k) {
            float v0 = (p0 < KC) ? mD[base + p0]          : FLT_MAX;
            float v1 = (p1 < KC) ? mD[base + KC + p1]     : FLT_MAX;
            float v2 = (p2 < KC) ? mD[base + 2 * KC + p2] : FLT_MAX;
            float v3 = (p3 < KC) ? mD[base + 3 * KC + p3] : FLT_MAX;
            float bv = v0; int bs = 0;
            if (v1 < bv) { bv = v1; bs = 1; }
            if (v2 < bv) { bv = v2; bs = 2; }
            if (v3 < bv) { bv = v3; bs = 3; }
            int off = (bs == 0) ? p0 : (bs == 1) ? p1 : (bs == 2) ? p2 : p3;
            outp[k] = mI[base + bs * KC + off];
            if (bs == 0) ++p0; else if (bs == 1) ++p1; else if (bs == 2) ++p2; else ++p3;
        }
    }
}

// ------- k_out: fp64 exact re-rank of 64 coarse candidates -> top-10 -> gather-max -------
__global__ __launch_bounds__(128) void k_out(const float* __restrict__ y,
                                             const float* __restrict__ ptsT,
                                             const int* __restrict__ knnI,
                                             float* __restrict__ out) {
    __shared__ float  qs[Dims];
    __shared__ int    cidx[SEG * KC];
    __shared__ double d2s[SEG * KC];
    __shared__ int    nb[KNN];
    const int n = blockIdx.x;
    const int t = threadIdx.x;

    if (t < Dims) qs[t] = ptsT[n * Dims + t];
    if (t < SEG * KC)
        cidx[t] = knnI[(size_t)((t >> 4) * Npts + n) * KC + (t & 15)];
    __syncthreads();

    if (t < SEG * KC) {
        const int j = cidx[t];
        double acc = 0.0;
#pragma unroll
        for (int d4 = 0; d4 < Dims / 4; ++d4) {
            const float4 pv = *reinterpret_cast<const float4*>(&ptsT[j * Dims + d4 * 4]);
            const float4 qv = *reinterpret_cast<const float4*>(&qs[d4 * 4]);
            double e0 = (double)qv.x - (double)pv.x;
            double e1 = (double)qv.y - (double)pv.y;
            double e2 = (double)qv.z - (double)pv.z;
            double e3 = (double)qv.w - (double)pv.w;
            acc = fma(e0, e0, acc); acc = fma(e1, e1, acc);
            acc = fma(e2, e2, acc); acc = fma(e3, e3, acc);
        }
        d2s[t] = acc;
    }
    __syncthreads();

    // parallel rank selection over 64 candidates, strict order (d2, idx)
    if (t < SEG * KC) {
        const double dv = d2s[t]; const int ji = cidx[t];
        int rank = 0;
        for (int c = 0; c < SEG * KC; ++c) {
            bool less = (d2s[c] < dv) || (d2s[c] == dv && cidx[c] < ji);
            rank += less ? 1 : 0;
        }
        if (rank < KNN) nb[rank] = ji;
    }
    __syncthreads();

    float m = -FLT_MAX;
#pragma unroll
    for (int k = 0; k < KNN; ++k)
        m = fmaxf(m, y[(size_t)nb[k] * Oout + t]);
    out[(size_t)n * Oout + t] = m;
}

// ---------------- launcher ----------------
extern "C" void kernel_launch(void* const* d_in, const int* in_sizes, int n_in,
                              void* d_out, int out_size, void* d_ws, size_t ws_size,
                              hipStream_t stream) {
    const float* x = (const float*)d_in[0];   // (1, 64, 16384)
    const float* W = (const float*)d_in[1];   // (128, 64)
    const float* b = (const float*)d_in[2];   // (128,)
    float* out = (float*)d_out;

    float* ws   = (float*)d_ws;
    float* sq   = ws;                                   // 16384
    float* ptsT = ws + Npts;                            // N*D      (4 MB)
    float* y    = ptsT + Npts * Dims;                   // N*O      (8 MB)
    unsigned short* xh = (unsigned short*)(y + Npts * Oout);   // N*D bf16 (2 MB)
    unsigned short* xl = xh + Npts * Dims;                     // N*D bf16 (2 MB)
    int* knnI   = (int*)(xl + Npts * Dims);             // SEG*N*KC (4 MB)

    k_tr <<<Npts / 64, 256, 0, stream>>>(x, ptsT, xh, xl, sq);
    k_y  <<<Npts / 8, 256, 0, stream>>>(ptsT, W, b, y);
    k_knn<<<(Npts / QT) * SEG, 256, 0, stream>>>(xh, xl, sq, knnI);
    k_out<<<Npts, 128, 0, stream>>>(y, ptsT, knnI, out);
}

// Round 4
// 594.797 us; speedup vs baseline: 2.8776x; 1.6619x over previous
//
#include <hip/hip_runtime.h>
#include <hip/hip_bf16.h>
#include <float.h>

#define Npts 16384
#define Dims 64
#define Oout 128
#define KNN  10
#define KC   16                      // coarse top-K per (segment, query)
#define SEG  4
#define QT   64                      // queries per k_knn block
#define CT   64                      // candidates per chunk
#define QCAP 32                      // LDS queue capacity per query per chunk
#define CAND_PER_SEG (Npts / SEG)    // 4096
#define CHUNKS (CAND_PER_SEG / CT)   // 64

typedef __attribute__((ext_vector_type(8))) short s16x8;
typedef __attribute__((ext_vector_type(4))) float f32x4;

__device__ __forceinline__ unsigned short f2bf(float f) {
    unsigned u = __float_as_uint(f);
    return (unsigned short)((u + 0x7FFFu + ((u >> 16) & 1u)) >> 16);
}
__device__ __forceinline__ float bf2f(unsigned short b) {
    return __uint_as_float(((unsigned)b) << 16);
}

__device__ __forceinline__ void gl_lds16(const void* g, void* s) {
    __builtin_amdgcn_global_load_lds(
        (const __attribute__((address_space(1))) void*)g,
        (__attribute__((address_space(3))) void*)s,
        16, 0, 0);
}

__device__ __forceinline__ void insert16(float (&bd)[KC], int (&bi)[KC], float s, int j) {
    if (s < bd[KC - 1]) {
#pragma unroll
        for (int k = KC - 1; k >= 1; --k) {
            bool up = bd[k - 1] > s;
            float nd = up ? bd[k - 1] : ((bd[k] > s) ? s : bd[k]);
            int   ni = up ? bi[k - 1] : ((bd[k] > s) ? j : bi[k]);
            bd[k] = nd; bi[k] = ni;
        }
        bool u0 = bd[0] > s;
        bi[0] = u0 ? j : bi[0];
        bd[0] = u0 ? s : bd[0];
    }
}

// ------- k_tr: transpose + bf16 hi/lo split + sq -------
__global__ __launch_bounds__(256) void k_tr(const float* __restrict__ x,
                                            float* __restrict__ ptsT,
                                            unsigned short* __restrict__ xh,
                                            unsigned short* __restrict__ xl,
                                            float* __restrict__ sq) {
    __shared__ float tile[64][65];
    const int b = blockIdx.x;
    for (int i = threadIdx.x; i < 64 * 64; i += 256) {
        int d = i >> 6, p = i & 63;
        tile[d][p] = x[d * Npts + b * 64 + p];
    }
    __syncthreads();
    for (int i = threadIdx.x; i < 64 * 64; i += 256) {
        int p = i >> 6, d = i & 63;
        float v = tile[d][p];
        ptsT[(b * 64 + p) * 64 + d] = v;
        unsigned short h = f2bf(v);
        float lo = v - bf2f(h);
        xh[(b * 64 + p) * 64 + d] = h;
        xl[(b * 64 + p) * 64 + d] = f2bf(lo);
    }
    __syncthreads();
    if (threadIdx.x < 64) {
        int p = threadIdx.x;
        float a = 0.f;
#pragma unroll
        for (int d = 0; d < 64; ++d) { float v = tile[d][p]; a = fmaf(v, v, a); }
        sq[b * 64 + p] = a;
    }
}

// ------- k_y: y[n][o] = W[o]·pts[n] + b[o], LDS-tiled -------
__global__ __launch_bounds__(256) void k_y(const float* __restrict__ ptsT,
                                           const float* __restrict__ W,
                                           const float* __restrict__ bias,
                                           float* __restrict__ y) {
    __shared__ float wsh[128][65];
    __shared__ float xs[8][64];
    const int t = threadIdx.x;
    const int nb = blockIdx.x * 8;
    for (int i = t; i < 128 * 64; i += 256) {
        int o = i >> 6, d = i & 63;
        wsh[o][d] = W[i];
    }
    for (int i = t; i < 8 * 64; i += 256) {
        int n8 = i >> 6, d = i & 63;
        xs[n8][d] = ptsT[(nb + n8) * 64 + d];
    }
    __syncthreads();
    const int o = t & 127, nn = t >> 7;
    float a0 = bias[o], a1 = a0, a2 = a0, a3 = a0;
#pragma unroll
    for (int d = 0; d < 64; ++d) {
        float wv = wsh[o][d];
        a0 = fmaf(xs[nn * 4 + 0][d], wv, a0);
        a1 = fmaf(xs[nn * 4 + 1][d], wv, a1);
        a2 = fmaf(xs[nn * 4 + 2][d], wv, a2);
        a3 = fmaf(xs[nn * 4 + 3][d], wv, a3);
    }
    y[(nb + nn * 4 + 0) * 128 + o] = a0;
    y[(nb + nn * 4 + 1) * 128 + o] = a1;
    y[(nb + nn * 4 + 2) * 128 + o] = a2;
    y[(nb + nn * 4 + 3) * 128 + o] = a3;
}

// ------- k_knn: MFMA distances + tau-filter + LDS queue + rare insert -------
// grid: 256 qblocks x SEG. block 256 = 4 waves; wave w owns queries w*16..+15.
// S^T = mfma(A=cand, B=query): lane holds 4 scores for query (lane&15).
__global__ __launch_bounds__(256, 4) void k_knn(const unsigned short* __restrict__ xh,
                                                const unsigned short* __restrict__ xl,
                                                const float* __restrict__ sq,
                                                int* __restrict__ knnI) {
    __shared__ char smem[2 * 16384];       // staging dbuf (hi 8KB + lo 8KB each)
    __shared__ float2 qq[4][16][QCAP + 1]; // accept queue, stride 33 (bank-spread)
    __shared__ int    qcnt[4][16];

    const int t    = threadIdx.x;
    const int w    = t >> 6;
    const int l    = t & 63;
    const int g    = l >> 4;           // k-group / C-row group
    const int q15  = l & 15;           // query column within wave
    const int qblk = blockIdx.x & 255;
    const int seg  = blockIdx.x >> 8;
    const int qbase = qblk * QT;
    const int swz  = (l & 7) << 4;     // A-read XOR swizzle

    if (t < 64) ((int*)qcnt)[t] = 0;

    // B frags (queries): one-time global loads
    const int q = qbase + w * 16 + q15;
    const char* qhp = (const char*)xh + (size_t)q * 128;
    const char* qlp = (const char*)xl + (size_t)q * 128;
    const s16x8 qh0 = *(const s16x8*)(qhp + g * 16);
    const s16x8 qh1 = *(const s16x8*)(qhp + 64 + g * 16);
    const s16x8 ql0 = *(const s16x8*)(qlp + g * 16);
    const s16x8 ql1 = *(const s16x8*)(qlp + 64 + g * 16);

    // staging source lane offset (pre-swizzled global -> linear LDS dest)
    const int loff = ((l >> 3) << 7) + (((l & 7) ^ (l >> 3)) << 4);

    float bd[KC]; int bi[KC];
#pragma unroll
    for (int k = 0; k < KC; ++k) { bd[k] = FLT_MAX; bi[k] = -1; }
    float tau = FLT_MAX;

    // prologue: stage chunk 0 into buf 0
    {
        const size_t sb = (size_t)(seg * CAND_PER_SEG + w * 16) * 128 + loff;
        const char* sH = (const char*)xh + sb;
        const char* sL = (const char*)xl + sb;
        char* dH = smem + w * 2048;
        gl_lds16(sH, dH);           gl_lds16(sH + 1024, dH + 1024);
        gl_lds16(sL, dH + 8192);    gl_lds16(sL + 1024, dH + 9216);
    }
    __syncthreads();

    for (int c = 0; c < CHUNKS; ++c) {
        if (c + 1 < CHUNKS) {
            const size_t sb = (size_t)(seg * CAND_PER_SEG + (c + 1) * CT + w * 16) * 128 + loff;
            const char* sH = (const char*)xh + sb;
            const char* sL = (const char*)xl + sb;
            char* dH = smem + ((c + 1) & 1) * 16384 + w * 2048;
            gl_lds16(sH, dH);           gl_lds16(sH + 1024, dH + 1024);
            gl_lds16(sL, dH + 8192);    gl_lds16(sL + 1024, dH + 9216);
        }

        const char* hb = smem + (c & 1) * 16384;
        const char* lb = hb + 8192;
        const int jb = seg * CAND_PER_SEG + c * CT;
#pragma unroll
        for (int ct = 0; ct < 4; ++ct) {
            const int ro = (ct * 16 + q15) * 128;
            const int o0 = (g * 16) ^ swz;
            const int o1 = (64 + g * 16) ^ swz;
            const s16x8 ah0 = *(const s16x8*)(hb + ro + o0);
            const s16x8 ah1 = *(const s16x8*)(hb + ro + o1);
            const s16x8 al0 = *(const s16x8*)(lb + ro + o0);
            const s16x8 al1 = *(const s16x8*)(lb + ro + o1);
            f32x4 acc = {0.f, 0.f, 0.f, 0.f};
            acc = __builtin_amdgcn_mfma_f32_16x16x32_bf16(ah0, qh0, acc, 0, 0, 0);
            acc = __builtin_amdgcn_mfma_f32_16x16x32_bf16(ah1, qh1, acc, 0, 0, 0);
            acc = __builtin_amdgcn_mfma_f32_16x16x32_bf16(ah0, ql0, acc, 0, 0, 0);
            acc = __builtin_amdgcn_mfma_f32_16x16x32_bf16(ah1, ql1, acc, 0, 0, 0);
            acc = __builtin_amdgcn_mfma_f32_16x16x32_bf16(al0, qh0, acc, 0, 0, 0);
            acc = __builtin_amdgcn_mfma_f32_16x16x32_bf16(al1, qh1, acc, 0, 0, 0);

            const int j0 = jb + ct * 16 + g * 4;
            const float4 s4 = *(const float4*)(sq + j0);
            const float ss[4] = {fmaf(-2.f, acc[0], s4.x), fmaf(-2.f, acc[1], s4.y),
                                 fmaf(-2.f, acc[2], s4.z), fmaf(-2.f, acc[3], s4.w)};
#pragma unroll
            for (int u = 0; u < 4; ++u) {
                if (ss[u] < tau) {   // rare after warm-up
                    int pos = atomicAdd(&qcnt[w][q15], 1);
                    if (pos < QCAP) {
                        qq[w][q15][pos] = make_float2(ss[u], __int_as_float(j0 + u));
                    } else {
                        insert16(bd, bi, ss[u], j0 + u);  // overflow fallback (chunk 0)
                    }
                }
            }
        }

        // drain this wave's queues (wave-private LDS; lockstep ordering)
        __builtin_amdgcn_wave_barrier();
        {
            int len = qcnt[w][q15];
            len = (len < QCAP) ? len : QCAP;
            for (int i = g; i < len; i += 4) {
                float2 e = qq[w][q15][i];
                insert16(bd, bi, e.x, __float_as_int(e.y));
            }
            __builtin_amdgcn_wave_barrier();
            if (g == 0) qcnt[w][q15] = 0;
            // tau = min over the 4 owner lanes' 16th-best (safe upper bound)
            float t15 = bd[KC - 1];
            t15 = fminf(t15, __shfl_xor(t15, 16, 64));
            t15 = fminf(t15, __shfl_xor(t15, 32, 64));
            tau = t15;
        }
        __syncthreads();   // staging drain + buffer swap
    }

    // merge 4 per-lane sorted lists per query (reuse staging LDS)
    float* mD = (float*)smem;
    int*   mI = (int*)(smem + 16384);
    const int qb = w * 16 + q15;
#pragma unroll
    for (int k = 0; k < KC; ++k) {
        mD[(qb * 4 + g) * KC + k] = bd[k];
        mI[(qb * 4 + g) * KC + k] = bi[k];
    }
    __syncthreads();

    if (t < QT) {
        const int base = t * 4 * KC;
        int p0 = 0, p1 = 0, p2 = 0, p3 = 0;
        int* outp = knnI + (size_t)(seg * Npts + qbase + t) * KC;
        for (int k = 0; k < KC; ++k) {
            float v0 = (p0 < KC) ? mD[base + p0]          : FLT_MAX;
            float v1 = (p1 < KC) ? mD[base + KC + p1]     : FLT_MAX;
            float v2 = (p2 < KC) ? mD[base + 2 * KC + p2] : FLT_MAX;
            float v3 = (p3 < KC) ? mD[base + 3 * KC + p3] : FLT_MAX;
            float bv = v0; int bs = 0;
            if (v1 < bv) { bv = v1; bs = 1; }
            if (v2 < bv) { bv = v2; bs = 2; }
            if (v3 < bv) { bv = v3; bs = 3; }
            int off = (bs == 0) ? p0 : (bs == 1) ? p1 : (bs == 2) ? p2 : p3;
            outp[k] = mI[base + bs * KC + off];
            if (bs == 0) ++p0; else if (bs == 1) ++p1; else if (bs == 2) ++p2; else ++p3;
        }
    }
}

// ------- k_out: fp64 exact re-rank of 64 coarse candidates -> top-10 -> gather-max -------
__global__ __launch_bounds__(128) void k_out(const float* __restrict__ y,
                                             const float* __restrict__ ptsT,
                                             const int* __restrict__ knnI,
                                             float* __restrict__ out) {
    __shared__ float  qs[Dims];
    __shared__ int    cidx[SEG * KC];
    __shared__ double d2s[SEG * KC];
    __shared__ int    nb[KNN];
    const int n = blockIdx.x;
    const int t = threadIdx.x;

    if (t < Dims) qs[t] = ptsT[n * Dims + t];
    if (t < SEG * KC)
        cidx[t] = knnI[(size_t)((t >> 4) * Npts + n) * KC + (t & 15)];
    __syncthreads();

    if (t < SEG * KC) {
        const int j = cidx[t];
        double acc = 0.0;
#pragma unroll
        for (int d4 = 0; d4 < Dims / 4; ++d4) {
            const float4 pv = *reinterpret_cast<const float4*>(&ptsT[j * Dims + d4 * 4]);
            const float4 qv = *reinterpret_cast<const float4*>(&qs[d4 * 4]);
            double e0 = (double)qv.x - (double)pv.x;
            double e1 = (double)qv.y - (double)pv.y;
            double e2 = (double)qv.z - (double)pv.z;
            double e3 = (double)qv.w - (double)pv.w;
            acc = fma(e0, e0, acc); acc = fma(e1, e1, acc);
            acc = fma(e2, e2, acc); acc = fma(e3, e3, acc);
        }
        d2s[t] = acc;
    }
    __syncthreads();

    if (t < SEG * KC) {
        const double dv = d2s[t]; const int ji = cidx[t];
        int rank = 0;
        for (int c = 0; c < SEG * KC; ++c) {
            bool less = (d2s[c] < dv) || (d2s[c] == dv && cidx[c] < ji);
            rank += less ? 1 : 0;
        }
        if (rank < KNN) nb[rank] = ji;
    }
    __syncthreads();

    float m = -FLT_MAX;
#pragma unroll
    for (int k = 0; k < KNN; ++k)
        m = fmaxf(m, y[(size_t)nb[k] * Oout + t]);
    out[(size_t)n * Oout + t] = m;
}

// ---------------- launcher ----------------
extern "C" void kernel_launch(void* const* d_in, const int* in_sizes, int n_in,
                              void* d_out, int out_size, void* d_ws, size_t ws_size,
                              hipStream_t stream) {
    const float* x = (const float*)d_in[0];   // (1, 64, 16384)
    const float* W = (const float*)d_in[1];   // (128, 64)
    const float* b = (const float*)d_in[2];   // (128,)
    float* out = (float*)d_out;

    float* ws   = (float*)d_ws;
    float* sq   = ws;                                   // 16384
    float* ptsT = ws + Npts;                            // N*D
    float* y    = ptsT + Npts * Dims;                   // N*O
    unsigned short* xh = (unsigned short*)(y + Npts * Oout);   // N*D bf16
    unsigned short* xl = xh + Npts * Dims;                     // N*D bf16
    int* knnI   = (int*)(xl + Npts * Dims);             // SEG*N*KC

    k_tr <<<Npts / 64, 256, 0, stream>>>(x, ptsT, xh, xl, sq);
    k_y  <<<Npts / 8, 256, 0, stream>>>(ptsT, W, b, y);
    k_knn<<<(Npts / QT) * SEG, 256, 0, stream>>>(xh, xl, sq, knnI);
    k_out<<<Npts, 128, 0, stream>>>(y, ptsT, knnI, out);
}

// Round 5
// 594.407 us; speedup vs baseline: 2.8795x; 1.0007x over previous
//
#include <hip/hip_runtime.h>
#include <hip/hip_bf16.h>
#include <float.h>

#define Npts 16384
#define Dims 64
#define Oout 128
#define KNN  10
#define KC   16                      // coarse top-K per (segment, query)
#define SEG  4
#define QT   64                      // queries per k_knn block
#define CT   128                     // candidates per chunk (hi-plane only)
#define QCAP 24                      // LDS queue capacity per query per chunk
#define CAND_PER_SEG (Npts / SEG)    // 4096
#define CHUNKS (CAND_PER_SEG / CT)   // 32

typedef __attribute__((ext_vector_type(8))) short s16x8;
typedef __attribute__((ext_vector_type(4))) float f32x4;

__device__ __forceinline__ unsigned short f2bf(float f) {
    unsigned u = __float_as_uint(f);
    return (unsigned short)((u + 0x7FFFu + ((u >> 16) & 1u)) >> 16);
}

__device__ __forceinline__ void gl_lds16(const void* g, void* s) {
    __builtin_amdgcn_global_load_lds(
        (const __attribute__((address_space(1))) void*)g,
        (__attribute__((address_space(3))) void*)s,
        16, 0, 0);
}

__device__ __forceinline__ void insert16(float (&bd)[KC], int (&bi)[KC], float s, int j) {
    if (s < bd[KC - 1]) {
#pragma unroll
        for (int k = KC - 1; k >= 1; --k) {
            bool up = bd[k - 1] > s;
            float nd = up ? bd[k - 1] : ((bd[k] > s) ? s : bd[k]);
            int   ni = up ? bi[k - 1] : ((bd[k] > s) ? j : bi[k]);
            bd[k] = nd; bi[k] = ni;
        }
        bool u0 = bd[0] > s;
        bi[0] = u0 ? j : bi[0];
        bd[0] = u0 ? s : bd[0];
    }
}

// ------- k_tr: transpose + bf16 hi split + sq -------
__global__ __launch_bounds__(256) void k_tr(const float* __restrict__ x,
                                            float* __restrict__ ptsT,
                                            unsigned short* __restrict__ xh,
                                            float* __restrict__ sq) {
    __shared__ float tile[64][65];
    const int b = blockIdx.x;
    for (int i = threadIdx.x; i < 64 * 64; i += 256) {
        int d = i >> 6, p = i & 63;
        tile[d][p] = x[d * Npts + b * 64 + p];
    }
    __syncthreads();
    for (int i = threadIdx.x; i < 64 * 64; i += 256) {
        int p = i >> 6, d = i & 63;
        float v = tile[d][p];
        ptsT[(b * 64 + p) * 64 + d] = v;
        xh[(b * 64 + p) * 64 + d] = f2bf(v);
    }
    __syncthreads();
    if (threadIdx.x < 64) {
        int p = threadIdx.x;
        float a = 0.f;
#pragma unroll
        for (int d = 0; d < 64; ++d) { float v = tile[d][p]; a = fmaf(v, v, a); }
        sq[b * 64 + p] = a;
    }
}

// ------- k_y: y[n][o] = W[o]·pts[n] + b[o], LDS-tiled -------
__global__ __launch_bounds__(256) void k_y(const float* __restrict__ ptsT,
                                           const float* __restrict__ W,
                                           const float* __restrict__ bias,
                                           float* __restrict__ y) {
    __shared__ float wsh[128][65];
    __shared__ float xs[8][64];
    const int t = threadIdx.x;
    const int nb = blockIdx.x * 8;
    for (int i = t; i < 128 * 64; i += 256) {
        int o = i >> 6, d = i & 63;
        wsh[o][d] = W[i];
    }
    for (int i = t; i < 8 * 64; i += 256) {
        int n8 = i >> 6, d = i & 63;
        xs[n8][d] = ptsT[(nb + n8) * 64 + d];
    }
    __syncthreads();
    const int o = t & 127, nn = t >> 7;
    float a0 = bias[o], a1 = a0, a2 = a0, a3 = a0;
#pragma unroll
    for (int d = 0; d < 64; ++d) {
        float wv = wsh[o][d];
        a0 = fmaf(xs[nn * 4 + 0][d], wv, a0);
        a1 = fmaf(xs[nn * 4 + 1][d], wv, a1);
        a2 = fmaf(xs[nn * 4 + 2][d], wv, a2);
        a3 = fmaf(xs[nn * 4 + 3][d], wv, a3);
    }
    y[(nb + nn * 4 + 0) * 128 + o] = a0;
    y[(nb + nn * 4 + 1) * 128 + o] = a1;
    y[(nb + nn * 4 + 2) * 128 + o] = a2;
    y[(nb + nn * 4 + 3) * 128 + o] = a3;
}

// ------- k_knn: hi-only MFMA distances + tau-filter + LDS queue -------
// grid: 256 qblocks x SEG. block 256 = 4 waves; wave w owns queries w*16..+15.
// S^T = mfma(A=cand, B=query): lane holds 4 scores for query (lane&15).
__global__ __launch_bounds__(256, 4) void k_knn(const unsigned short* __restrict__ xh,
                                                const float* __restrict__ sq,
                                                int* __restrict__ knnI) {
    __shared__ char smem[2][16384];          // staging dbuf: 128 cand x 128 B (hi)
    __shared__ float2 qq[4][16][QCAP + 1];   // accept queue, stride 25 entries
    __shared__ int    qcnt[4][16];

    const int t    = threadIdx.x;
    const int w    = t >> 6;
    const int l    = t & 63;
    const int g    = l >> 4;           // k-group / D-row group
    const int q15  = l & 15;           // query column within wave
    const int qblk = blockIdx.x & 255;
    const int seg  = blockIdx.x >> 8;
    const int qbase = qblk * QT;
    const int swz  = (l & 7) << 4;     // A-read XOR swizzle (row&7 == q15&7)

    if (t < 64) ((int*)qcnt)[t] = 0;

    // B frags (queries), one-time global loads: k-slices g*8.. and 32+g*8..
    const int q = qbase + w * 16 + q15;
    const char* qhp = (const char*)xh + (size_t)q * 128;
    const s16x8 qh0 = *(const s16x8*)(qhp + g * 16);
    const s16x8 qh1 = *(const s16x8*)(qhp + 64 + g * 16);

    // staging source lane offset (pre-swizzled global -> linear LDS dest)
    const int loff = ((l >> 3) << 7) + (((l & 7) ^ (l >> 3)) << 4);

    float bd[KC]; int bi[KC];
#pragma unroll
    for (int k = 0; k < KC; ++k) { bd[k] = FLT_MAX; bi[k] = -1; }
    float tau = FLT_MAX;

    // prologue: stage chunk 0 (hi, 16 KB) into buf 0; wave w stages cands w*32..+31
    {
        const size_t sb = (size_t)(seg * CAND_PER_SEG + w * 32) * 128 + loff;
        const char* sH = (const char*)xh + sb;
        char* dH = smem[0] + w * 4096;
#pragma unroll
        for (int i = 0; i < 4; ++i) gl_lds16(sH + i * 1024, dH + i * 1024);
    }
    __syncthreads();

    for (int c = 0; c < CHUNKS; ++c) {
        if (c + 1 < CHUNKS) {
            const size_t sb = (size_t)(seg * CAND_PER_SEG + (c + 1) * CT + w * 32) * 128 + loff;
            const char* sH = (const char*)xh + sb;
            char* dH = smem[(c + 1) & 1] + w * 4096;
#pragma unroll
            for (int i = 0; i < 4; ++i) gl_lds16(sH + i * 1024, dH + i * 1024);
        }

        const char* hb = smem[c & 1];
        const int jb = seg * CAND_PER_SEG + c * CT;
#pragma unroll
        for (int ct = 0; ct < 8; ++ct) {
            const int ro = (ct * 16 + q15) * 128;
            const s16x8 ah0 = *(const s16x8*)(hb + ro + ((g * 16) ^ swz));
            const s16x8 ah1 = *(const s16x8*)(hb + ro + ((64 + g * 16) ^ swz));
            f32x4 acc = {0.f, 0.f, 0.f, 0.f};
            acc = __builtin_amdgcn_mfma_f32_16x16x32_bf16(ah0, qh0, acc, 0, 0, 0);
            acc = __builtin_amdgcn_mfma_f32_16x16x32_bf16(ah1, qh1, acc, 0, 0, 0);

            const int j0 = jb + ct * 16 + g * 4;
            const float4 s4 = *(const float4*)(sq + j0);
            const float ss[4] = {fmaf(-2.f, acc[0], s4.x), fmaf(-2.f, acc[1], s4.y),
                                 fmaf(-2.f, acc[2], s4.z), fmaf(-2.f, acc[3], s4.w)};
            if (c == 0) {
                // seed pass: direct insert (tau not yet valid)
#pragma unroll
                for (int u = 0; u < 4; ++u) insert16(bd, bi, ss[u], j0 + u);
            } else {
                const float mn = fminf(fminf(ss[0], ss[1]), fminf(ss[2], ss[3]));
                if (mn < tau) {   // rare after warm-up (exec-masked skip)
#pragma unroll
                    for (int u = 0; u < 4; ++u) {
                        if (ss[u] < tau) {
                            int pos = atomicAdd(&qcnt[w][q15], 1);
                            if (pos < QCAP)
                                qq[w][q15][pos] = make_float2(ss[u], __int_as_float(j0 + u));
                            else
                                insert16(bd, bi, ss[u], j0 + u);  // overflow fallback
                        }
                    }
                }
            }
        }

        // drain this wave's queues (wave-private LDS, lockstep)
        __builtin_amdgcn_wave_barrier();
        {
            int len = qcnt[w][q15];
            len = (len < QCAP) ? len : QCAP;
            for (int i = g; i < len; i += 4) {
                float2 e = qq[w][q15][i];
                insert16(bd, bi, e.x, __float_as_int(e.y));
            }
            __builtin_amdgcn_wave_barrier();
            if (g == 0) qcnt[w][q15] = 0;
            // tau = min over the 4 owner lanes' 16th-best (safe upper bound)
            float t15 = bd[KC - 1];
            t15 = fminf(t15, __shfl_xor(t15, 16, 64));
            t15 = fminf(t15, __shfl_xor(t15, 32, 64));
            tau = t15;
        }
        __syncthreads();   // staging drain + buffer swap
    }

    // merge 4 per-lane sorted lists per query (reuse staging LDS: 16KB + 16KB)
    float* mD = (float*)smem[0];
    int*   mI = (int*)smem[1];
    const int qb = w * 16 + q15;
#pragma unroll
    for (int k = 0; k < KC; ++k) {
        mD[(qb * 4 + g) * KC + k] = bd[k];
        mI[(qb * 4 + g) * KC + k] = bi[k];
    }
    __syncthreads();

    if (t < QT) {
        const int base = t * 4 * KC;
        int p0 = 0, p1 = 0, p2 = 0, p3 = 0;
        int* outp = knnI + (size_t)(seg * Npts + qbase + t) * KC;
        for (int k = 0; k < KC; ++k) {
            float v0 = (p0 < KC) ? mD[base + p0]          : FLT_MAX;
            float v1 = (p1 < KC) ? mD[base + KC + p1]     : FLT_MAX;
            float v2 = (p2 < KC) ? mD[base + 2 * KC + p2] : FLT_MAX;
            float v3 = (p3 < KC) ? mD[base + 3 * KC + p3] : FLT_MAX;
            float bv = v0; int bs = 0;
            if (v1 < bv) { bv = v1; bs = 1; }
            if (v2 < bv) { bv = v2; bs = 2; }
            if (v3 < bv) { bv = v3; bs = 3; }
            int off = (bs == 0) ? p0 : (bs == 1) ? p1 : (bs == 2) ? p2 : p3;
            outp[k] = mI[base + bs * KC + off];
            if (bs == 0) ++p0; else if (bs == 1) ++p1; else if (bs == 2) ++p2; else ++p3;
        }
    }
}

// ------- k_out: fp64 exact re-rank of 64 coarse candidates -> top-10 -> gather-max -------
__global__ __launch_bounds__(128) void k_out(const float* __restrict__ y,
                                             const float* __restrict__ ptsT,
                                             const int* __restrict__ knnI,
                                             float* __restrict__ out) {
    __shared__ float  qs[Dims];
    __shared__ int    cidx[SEG * KC];
    __shared__ double d2s[SEG * KC];
    __shared__ int    nb[KNN];
    const int n = blockIdx.x;
    const int t = threadIdx.x;

    if (t < Dims) qs[t] = ptsT[n * Dims + t];
    if (t < SEG * KC)
        cidx[t] = knnI[(size_t)((t >> 4) * Npts + n) * KC + (t & 15)];
    __syncthreads();

    if (t < SEG * KC) {
        const int j = cidx[t];
        double acc = 0.0;
#pragma unroll
        for (int d4 = 0; d4 < Dims / 4; ++d4) {
            const float4 pv = *reinterpret_cast<const float4*>(&ptsT[j * Dims + d4 * 4]);
            const float4 qv = *reinterpret_cast<const float4*>(&qs[d4 * 4]);
            double e0 = (double)qv.x - (double)pv.x;
            double e1 = (double)qv.y - (double)pv.y;
            double e2 = (double)qv.z - (double)pv.z;
            double e3 = (double)qv.w - (double)pv.w;
            acc = fma(e0, e0, acc); acc = fma(e1, e1, acc);
            acc = fma(e2, e2, acc); acc = fma(e3, e3, acc);
        }
        d2s[t] = acc;
    }
    __syncthreads();

    if (t < SEG * KC) {
        const double dv = d2s[t]; const int ji = cidx[t];
        int rank = 0;
        for (int c = 0; c < SEG * KC; ++c) {
            bool less = (d2s[c] < dv) || (d2s[c] == dv && cidx[c] < ji);
            rank += less ? 1 : 0;
        }
        if (rank < KNN) nb[rank] = ji;
    }
    __syncthreads();

    float m = -FLT_MAX;
#pragma unroll
    for (int k = 0; k < KNN; ++k)
        m = fmaxf(m, y[(size_t)nb[k] * Oout + t]);
    out[(size_t)n * Oout + t] = m;
}

// ---------------- launcher ----------------
extern "C" void kernel_launch(void* const* d_in, const int* in_sizes, int n_in,
                              void* d_out, int out_size, void* d_ws, size_t ws_size,
                              hipStream_t stream) {
    const float* x = (const float*)d_in[0];   // (1, 64, 16384)
    const float* W = (const float*)d_in[1];   // (128, 64)
    const float* b = (const float*)d_in[2];   // (128,)
    float* out = (float*)d_out;

    float* ws   = (float*)d_ws;
    float* sq   = ws;                                   // 16384
    float* ptsT = ws + Npts;                            // N*D  (4 MB)
    float* y    = ptsT + Npts * Dims;                   // N*O  (8 MB)
    unsigned short* xh = (unsigned short*)(y + Npts * Oout);  // N*D bf16 (2 MB)
    int* knnI   = (int*)(xh + Npts * Dims);             // SEG*N*KC (4 MB)

    k_tr <<<Npts / 64, 256, 0, stream>>>(x, ptsT, xh, sq);
    k_y  <<<Npts / 8, 256, 0, stream>>>(ptsT, W, b, y);
    k_knn<<<(Npts / QT) * SEG, 256, 0, stream>>>(xh, sq, knnI);
    k_out<<<Npts, 128, 0, stream>>>(y, ptsT, knnI, out);
}

// Round 6
// 431.160 us; speedup vs baseline: 3.9697x; 1.3786x over previous
//
#include <hip/hip_runtime.h>
#include <hip/hip_bf16.h>
#include <float.h>

#define Npts 16384
#define Dims 64
#define Oout 128
#define KNN  10
#define KC   16                      // coarse top-K per (segment, query) written out
#define LC   12                      // per-lane coarse list (tau source)
#define SEG  4
#define QT   64                      // queries per k_knn block
#define CT   128                     // candidates per chunk (hi-plane only)
#define QCAP 8                       // per-lane queue capacity per chunk
#define QPAD 9                       // padded entries per lane region
#define CAND_PER_SEG (Npts / SEG)    // 4096
#define CHUNKS (CAND_PER_SEG / CT)   // 32

typedef __attribute__((ext_vector_type(8))) short s16x8;
typedef __attribute__((ext_vector_type(4))) float f32x4;

__device__ __forceinline__ unsigned short f2bf(float f) {
    unsigned u = __float_as_uint(f);
    return (unsigned short)((u + 0x7FFFu + ((u >> 16) & 1u)) >> 16);
}

__device__ __forceinline__ void gl_lds16(const void* g, void* s) {
    __builtin_amdgcn_global_load_lds(
        (const __attribute__((address_space(1))) void*)g,
        (__attribute__((address_space(3))) void*)s,
        16, 0, 0);
}

__device__ __forceinline__ void insertL(float (&bd)[LC], int (&bi)[LC], float s, int j) {
    if (s < bd[LC - 1]) {
#pragma unroll
        for (int k = LC - 1; k >= 1; --k) {
            bool up = bd[k - 1] > s;
            float nd = up ? bd[k - 1] : ((bd[k] > s) ? s : bd[k]);
            int   ni = up ? bi[k - 1] : ((bd[k] > s) ? j : bi[k]);
            bd[k] = nd; bi[k] = ni;
        }
        bool u0 = bd[0] > s;
        bi[0] = u0 ? j : bi[0];
        bd[0] = u0 ? s : bd[0];
    }
}

// ------- k_tr: transpose + bf16 hi split + sq -------
__global__ __launch_bounds__(256) void k_tr(const float* __restrict__ x,
                                            float* __restrict__ ptsT,
                                            unsigned short* __restrict__ xh,
                                            float* __restrict__ sq) {
    __shared__ float tile[64][65];
    const int b = blockIdx.x;
    for (int i = threadIdx.x; i < 64 * 64; i += 256) {
        int d = i >> 6, p = i & 63;
        tile[d][p] = x[d * Npts + b * 64 + p];
    }
    __syncthreads();
    for (int i = threadIdx.x; i < 64 * 64; i += 256) {
        int p = i >> 6, d = i & 63;
        float v = tile[d][p];
        ptsT[(b * 64 + p) * 64 + d] = v;
        xh[(b * 64 + p) * 64 + d] = f2bf(v);
    }
    __syncthreads();
    if (threadIdx.x < 64) {
        int p = threadIdx.x;
        float a = 0.f;
#pragma unroll
        for (int d = 0; d < 64; ++d) { float v = tile[d][p]; a = fmaf(v, v, a); }
        sq[b * 64 + p] = a;
    }
}

// ------- k_y: y[n][o] = W[o]·pts[n] + b[o], LDS-tiled -------
__global__ __launch_bounds__(256) void k_y(const float* __restrict__ ptsT,
                                           const float* __restrict__ W,
                                           const float* __restrict__ bias,
                                           float* __restrict__ y) {
    __shared__ float wsh[128][65];
    __shared__ float xs[8][64];
    const int t = threadIdx.x;
    const int nb = blockIdx.x * 8;
    for (int i = t; i < 128 * 64; i += 256) {
        int o = i >> 6, d = i & 63;
        wsh[o][d] = W[i];
    }
    for (int i = t; i < 8 * 64; i += 256) {
        int n8 = i >> 6, d = i & 63;
        xs[n8][d] = ptsT[(nb + n8) * 64 + d];
    }
    __syncthreads();
    const int o = t & 127, nn = t >> 7;
    float a0 = bias[o], a1 = a0, a2 = a0, a3 = a0;
#pragma unroll
    for (int d = 0; d < 64; ++d) {
        float wv = wsh[o][d];
        a0 = fmaf(xs[nn * 4 + 0][d], wv, a0);
        a1 = fmaf(xs[nn * 4 + 1][d], wv, a1);
        a2 = fmaf(xs[nn * 4 + 2][d], wv, a2);
        a3 = fmaf(xs[nn * 4 + 3][d], wv, a3);
    }
    y[(nb + nn * 4 + 0) * 128 + o] = a0;
    y[(nb + nn * 4 + 1) * 128 + o] = a1;
    y[(nb + nn * 4 + 2) * 128 + o] = a2;
    y[(nb + nn * 4 + 3) * 128 + o] = a3;
}

// ------- k_knn: hi-only MFMA distances + tau-filter + per-lane queue -------
// grid: 256 qblocks x SEG. block 256 = 4 waves; wave w owns queries w*16..+15.
// S^T = mfma(A=cand, B=query): lane holds 4 scores for query (lane&15).
__global__ __launch_bounds__(256, 4) void k_knn(const unsigned short* __restrict__ xh,
                                                const float* __restrict__ sq,
                                                int* __restrict__ knnI) {
    __shared__ char smem[2][16384];          // staging dbuf: 128 cand x 128 B (hi)
    __shared__ float2 qq[4][64][QPAD];       // per-lane accept queues (18.4 KB)

    const int t    = threadIdx.x;
    const int w    = t >> 6;
    const int l    = t & 63;
    const int g    = l >> 4;           // k-group / D-row group
    const int q15  = l & 15;           // query column within wave
    const int qblk = blockIdx.x & 255;
    const int seg  = blockIdx.x >> 8;
    const int qbase = qblk * QT;
    const int swz  = (l & 7) << 4;     // A-read XOR swizzle (row&7 == q15&7)

    // B frags (queries), one-time global loads: k-slices g*8.. and 32+g*8..
    const int q = qbase + w * 16 + q15;
    const char* qhp = (const char*)xh + (size_t)q * 128;
    const s16x8 qh0 = *(const s16x8*)(qhp + g * 16);
    const s16x8 qh1 = *(const s16x8*)(qhp + 64 + g * 16);

    // staging source lane offset (pre-swizzled global -> linear LDS dest)
    const int loff = ((l >> 3) << 7) + (((l & 7) ^ (l >> 3)) << 4);

    float bd[LC]; int bi[LC];
#pragma unroll
    for (int k = 0; k < LC; ++k) { bd[k] = FLT_MAX; bi[k] = -1; }
    float tau = FLT_MAX;

    // prologue: stage chunk 0 (hi, 16 KB) into buf 0; wave w stages cands w*32..+31
    {
        const size_t sb = (size_t)(seg * CAND_PER_SEG + w * 32) * 128 + loff;
        const char* sH = (const char*)xh + sb;
        char* dH = smem[0] + w * 4096;
#pragma unroll
        for (int i = 0; i < 4; ++i) gl_lds16(sH + i * 1024, dH + i * 1024);
    }
    __syncthreads();

    for (int c = 0; c < CHUNKS; ++c) {
        if (c + 1 < CHUNKS) {
            const size_t sb = (size_t)(seg * CAND_PER_SEG + (c + 1) * CT + w * 32) * 128 + loff;
            const char* sH = (const char*)xh + sb;
            char* dH = smem[(c + 1) & 1] + w * 4096;
#pragma unroll
            for (int i = 0; i < 4; ++i) gl_lds16(sH + i * 1024, dH + i * 1024);
        }

        const char* hb = smem[c & 1];
        const int jb = seg * CAND_PER_SEG + c * CT;
        int myq = 0;                       // per-lane queue count (register)
#pragma unroll
        for (int ct = 0; ct < 8; ++ct) {
            const int ro = (ct * 16 + q15) * 128;
            const s16x8 ah0 = *(const s16x8*)(hb + ro + ((g * 16) ^ swz));
            const s16x8 ah1 = *(const s16x8*)(hb + ro + ((64 + g * 16) ^ swz));
            f32x4 acc = {0.f, 0.f, 0.f, 0.f};
            acc = __builtin_amdgcn_mfma_f32_16x16x32_bf16(ah0, qh0, acc, 0, 0, 0);
            acc = __builtin_amdgcn_mfma_f32_16x16x32_bf16(ah1, qh1, acc, 0, 0, 0);

            const int j0 = jb + ct * 16 + g * 4;
            const float4 s4 = *(const float4*)(sq + j0);
            const float ss[4] = {fmaf(-2.f, acc[0], s4.x), fmaf(-2.f, acc[1], s4.y),
                                 fmaf(-2.f, acc[2], s4.z), fmaf(-2.f, acc[3], s4.w)};
            if (c == 0) {
                // seed pass: direct insert (tau not yet valid)
#pragma unroll
                for (int u = 0; u < 4; ++u) insertL(bd, bi, ss[u], j0 + u);
            } else {
#pragma unroll
                for (int u = 0; u < 4; ++u) {
                    if (ss[u] < tau) {            // cheap path: ~5 inst issued
                        int pos = myq++;
                        if (pos < QCAP)
                            qq[w][l][pos] = make_float2(ss[u], __int_as_float(j0 + u));
                        else
                            insertL(bd, bi, ss[u], j0 + u);   // rare overflow (execz-skipped)
                    }
                }
            }
        }

        // drain own queue (batched inserts: wave issues max-per-lane bodies, not sum)
        {
            int len = (myq < QCAP) ? myq : QCAP;
            for (int i = 0; i < len; ++i) {
                float2 e = qq[w][l][i];
                insertL(bd, bi, e.x, __float_as_int(e.y));
            }
            // tau = min over the 4 owner lanes' LC-th best (safe upper bound)
            float t15 = bd[LC - 1];
            t15 = fminf(t15, __shfl_xor(t15, 16, 64));
            t15 = fminf(t15, __shfl_xor(t15, 32, 64));
            tau = t15;
        }
        __syncthreads();   // staging drain + buffer swap
    }

    // merge 4 per-lane sorted lists (LC each) per query -> segment top-16
    float* mD = (float*)smem[0];         // 64q x 4g x LC = 3072 floats
    int*   mI = (int*)smem[1];
    const int qb = w * 16 + q15;
#pragma unroll
    for (int k = 0; k < LC; ++k) {
        mD[(qb * 4 + g) * LC + k] = bd[k];
        mI[(qb * 4 + g) * LC + k] = bi[k];
    }
    __syncthreads();

    if (t < QT) {
        const int base = t * 4 * LC;
        int p0 = 0, p1 = 0, p2 = 0, p3 = 0;
        int* outp = knnI + (size_t)(seg * Npts + qbase + t) * KC;
        for (int k = 0; k < KC; ++k) {
            float v0 = (p0 < LC) ? mD[base + p0]          : FLT_MAX;
            float v1 = (p1 < LC) ? mD[base + LC + p1]     : FLT_MAX;
            float v2 = (p2 < LC) ? mD[base + 2 * LC + p2] : FLT_MAX;
            float v3 = (p3 < LC) ? mD[base + 3 * LC + p3] : FLT_MAX;
            float bv = v0; int bs = 0;
            if (v1 < bv) { bv = v1; bs = 1; }
            if (v2 < bv) { bv = v2; bs = 2; }
            if (v3 < bv) { bv = v3; bs = 3; }
            int off = (bs == 0) ? p0 : (bs == 1) ? p1 : (bs == 2) ? p2 : p3;
            outp[k] = mI[base + bs * LC + off];
            if (bs == 0) ++p0; else if (bs == 1) ++p1; else if (bs == 2) ++p2; else ++p3;
        }
    }
}

// ------- k_out: fp64 exact re-rank of 64 coarse candidates -> top-10 -> gather-max -------
__global__ __launch_bounds__(128) void k_out(const float* __restrict__ y,
                                             const float* __restrict__ ptsT,
                                             const int* __restrict__ knnI,
                                             float* __restrict__ out) {
    __shared__ float  qs[Dims];
    __shared__ int    cidx[SEG * KC];
    __shared__ double d2s[SEG * KC];
    __shared__ int    nb[KNN];
    const int n = blockIdx.x;
    const int t = threadIdx.x;

    if (t < Dims) qs[t] = ptsT[n * Dims + t];
    if (t < SEG * KC)
        cidx[t] = knnI[(size_t)((t >> 4) * Npts + n) * KC + (t & 15)];
    __syncthreads();

    if (t < SEG * KC) {
        const int j = cidx[t];
        double acc = 0.0;
#pragma unroll
        for (int d4 = 0; d4 < Dims / 4; ++d4) {
            const float4 pv = *reinterpret_cast<const float4*>(&ptsT[j * Dims + d4 * 4]);
            const float4 qv = *reinterpret_cast<const float4*>(&qs[d4 * 4]);
            double e0 = (double)qv.x - (double)pv.x;
            double e1 = (double)qv.y - (double)pv.y;
            double e2 = (double)qv.z - (double)pv.z;
            double e3 = (double)qv.w - (double)pv.w;
            acc = fma(e0, e0, acc); acc = fma(e1, e1, acc);
            acc = fma(e2, e2, acc); acc = fma(e3, e3, acc);
        }
        d2s[t] = acc;
    }
    __syncthreads();

    if (t < SEG * KC) {
        const double dv = d2s[t]; const int ji = cidx[t];
        int rank = 0;
        for (int c = 0; c < SEG * KC; ++c) {
            bool less = (d2s[c] < dv) || (d2s[c] == dv && cidx[c] < ji);
            rank += less ? 1 : 0;
        }
        if (rank < KNN) nb[rank] = ji;
    }
    __syncthreads();

    float m = -FLT_MAX;
#pragma unroll
    for (int k = 0; k < KNN; ++k)
        m = fmaxf(m, y[(size_t)nb[k] * Oout + t]);
    out[(size_t)n * Oout + t] = m;
}

// ---------------- launcher ----------------
extern "C" void kernel_launch(void* const* d_in, const int* in_sizes, int n_in,
                              void* d_out, int out_size, void* d_ws, size_t ws_size,
                              hipStream_t stream) {
    const float* x = (const float*)d_in[0];   // (1, 64, 16384)
    const float* W = (const float*)d_in[1];   // (128, 64)
    const float* b = (const float*)d_in[2];   // (128,)
    float* out = (float*)d_out;

    float* ws   = (float*)d_ws;
    float* sq   = ws;                                   // 16384
    float* ptsT = ws + Npts;                            // N*D  (4 MB)
    float* y    = ptsT + Npts * Dims;                   // N*O  (8 MB)
    unsigned short* xh = (unsigned short*)(y + Npts * Oout);  // N*D bf16 (2 MB)
    int* knnI   = (int*)(xh + Npts * Dims);             // SEG*N*KC (4 MB)

    k_tr <<<Npts / 64, 256, 0, stream>>>(x, ptsT, xh, sq);
    k_y  <<<Npts / 8, 256, 0, stream>>>(ptsT, W, b, y);
    k_knn<<<(Npts / QT) * SEG, 256, 0, stream>>>(xh, sq, knnI);
    k_out<<<Npts, 128, 0, stream>>>(y, ptsT, knnI, out);
}